// Round 10
// baseline (297.382 us; speedup 1.0000x reference)
//
#include <hip/hip_runtime.h>
#include <hip/hip_bf16.h>
#include <math.h>

#define B_  32
#define S_  512
#define D_  512
#define E_  8
#define H_  2048
#define O_  512

typedef __bf16 bf16x8 __attribute__((ext_vector_type(8)));
typedef float  f32x4  __attribute__((ext_vector_type(4)));

#define GL2LDS(src, dst) \
  __builtin_amdgcn_global_load_lds((const __attribute__((address_space(1))) void*)(src), \
                                   (__attribute__((address_space(3))) void*)(dst), 16, 0, 0)

#define MFMA16(a, b, c) __builtin_amdgcn_mfma_f32_16x16x32_bf16((a), (b), (c), 0, 0, 0)

// tanh-form GELU (proven r4-r9: absmax 3.9e-3 unchanged)
__device__ __forceinline__ float gelu_fast(float v) {
  float w = v * fmaf(v * v, 0.0713548162f, 1.5957691216f);
  float e = __expf(-w);
  return v * __builtin_amdgcn_rcpf(1.0f + e);
}

// ---------------- cast x -> bf16 row-major, fused attention scores ----------------
__global__ __launch_bounds__(256) void cast_score_kernel(
    const float* __restrict__ x, const float* __restrict__ attn_w,
    ushort* __restrict__ xb, float* __restrict__ scores)
{
  const int t = threadIdx.x;
  const int r = t >> 5;
  const int cg = t & 31;
  const int row = blockIdx.x * 8 + r;
  const float* src  = x + (size_t)row * D_ + cg * 16;
  const float* wsrc = attn_w + cg * 16;
  ushort* dstp = xb + (size_t)row * D_ + cg * 16;
  float acc = 0.f;
#pragma unroll
  for (int k = 0; k < 4; ++k) {
    float4 v  = *(const float4*)(src + k * 4);
    float4 wv = *(const float4*)(wsrc + k * 4);
    acc += v.x * wv.x + v.y * wv.y + v.z * wv.z + v.w * wv.w;
    ushort4 o;
    o.x = __builtin_bit_cast(unsigned short, __float2bfloat16(v.x));
    o.y = __builtin_bit_cast(unsigned short, __float2bfloat16(v.y));
    o.z = __builtin_bit_cast(unsigned short, __float2bfloat16(v.z));
    o.w = __builtin_bit_cast(unsigned short, __float2bfloat16(v.w));
    *(ushort4*)(dstp + k * 4) = o;
  }
#pragma unroll
  for (int off = 16; off; off >>= 1) acc += __shfl_xor(acc, off);
  if (cg == 0) scores[row] = acc;
}

// ---------------- softmax over S per batch -> aw ----------------
__global__ __launch_bounds__(512) void softmax_aw_kernel(
    const float* __restrict__ scores, float* __restrict__ aw)
{
  __shared__ float red[8];
  __shared__ float mm, ss;
  const int t = threadIdx.x, b = blockIdx.x;
  float v = scores[b * S_ + t];
  float m = v;
#pragma unroll
  for (int off = 32; off; off >>= 1) m = fmaxf(m, __shfl_xor(m, off));
  if ((t & 63) == 0) red[t >> 6] = m;
  __syncthreads();
  if (t == 0) {
    float a = red[0];
    for (int i = 1; i < 8; ++i) a = fmaxf(a, red[i]);
    mm = a;
  }
  __syncthreads();
  float e = expf(v - mm);
  float s = e;
#pragma unroll
  for (int off = 32; off; off >>= 1) s += __shfl_xor(s, off);
  if ((t & 63) == 0) red[t >> 6] = s;
  __syncthreads();
  if (t == 0) {
    float a = 0.f;
    for (int i = 0; i < 8; ++i) a += red[i];
    ss = 1.f / a;
  }
  __syncthreads();
  aw[b * S_ + t] = e * ss;
}

// ---------------- pooled[b,d] = sum_s aw[b,s] * x[b,s,d] ----------------
__global__ __launch_bounds__(512) void pool_kernel(
    const float* __restrict__ x, const float* __restrict__ aw, float* __restrict__ pooled)
{
  __shared__ float sm[4][128];
  const int t = threadIdx.x;
  const int dl = t & 127;
  const int sh = t >> 7;
  const int b = blockIdx.y;
  const int d = blockIdx.x * 128 + dl;
  const float* xp  = x + (size_t)b * S_ * D_ + d;
  const float* awb = aw + b * S_;
  float acc = 0.f;
#pragma unroll 4
  for (int s = sh; s < S_; s += 4)
    acc = fmaf(awb[s], xp[(size_t)s * D_], acc);
  if (sh) sm[sh][dl] = acc;
  __syncthreads();
  if (sh == 0) pooled[b * D_ + d] = acc + sm[1][dl] + sm[2][dl] + sm[3][dl];
}

// ---------------- gates + top-2 + renorm + expert-sort ----------------
__global__ __launch_bounds__(256) void gate_psort_kernel(
    const float* __restrict__ pooled, const float* __restrict__ gate_w,
    const float* __restrict__ gate_b, int* __restrict__ gidx, float* __restrict__ gwt,
    int* __restrict__ psort)
{
  __shared__ float gl[32][8];
  const int t = threadIdx.x;
  const int b = t >> 3, ee = t & 7;
  float z = gate_b[ee];
  const float* pb = pooled + b * D_;
  for (int d = 0; d < D_; ++d) z = fmaf(pb[d], gate_w[d * E_ + ee], z);
  gl[b][ee] = z;
  __syncthreads();
  if (t < 32) {
    float ge[8];
    float zmax = gl[t][0];
    for (int i = 1; i < 8; ++i) zmax = fmaxf(zmax, gl[t][i]);
    float zs = 0.f;
    for (int i = 0; i < 8; ++i) { ge[i] = expf(gl[t][i] - zmax); zs += ge[i]; }
    for (int i = 0; i < 8; ++i) ge[i] /= zs;
    int i0 = 0;
    for (int i = 1; i < 8; ++i) if (ge[i] > ge[i0]) i0 = i;
    int i1 = -1;
    for (int i = 0; i < 8; ++i) if (i != i0 && (i1 < 0 || ge[i] > ge[i1])) i1 = i;
    float denom = ge[i0] + ge[i1] + 1e-9f;
    gidx[t * 2 + 0] = i0; gidx[t * 2 + 1] = i1;
    gwt[t * 2 + 0] = ge[i0] / denom; gwt[t * 2 + 1] = ge[i1] / denom;
  }
  __syncthreads();
  if (t == 0) {
    int cnt[E_] = {}, pos[E_];
    for (int p = 0; p < 2 * B_; ++p) cnt[gidx[p]]++;
    int s = 0;
    for (int e2 = 0; e2 < E_; ++e2) { pos[e2] = s; s += cnt[e2]; }
    for (int p = 0; p < 2 * B_; ++p) psort[pos[gidx[p]]++] = p;
  }
}

// ---------------- [z][R][C] f32 -> [z][C][R] bf16 ----------------
__global__ void transpose_cast_kernel(const float* __restrict__ in,
                                      __hip_bfloat16* __restrict__ outT, int R, int C)
{
  __shared__ float tile[32][33];
  const int z = blockIdx.z;
  const float* inz = in + (size_t)z * R * C;
  __hip_bfloat16* outz = outT + (size_t)z * R * C;
  const int c0 = blockIdx.x * 32, r0 = blockIdx.y * 32;
  const int tx = threadIdx.x, ty = threadIdx.y;
#pragma unroll
  for (int jj = 0; jj < 4; ++jj) {
    int r = r0 + ty + jj * 8;
    tile[ty + jj * 8][tx] = inz[(size_t)r * C + c0 + tx];
  }
  __syncthreads();
#pragma unroll
  for (int jj = 0; jj < 4; ++jj) {
    int c = c0 + ty + jj * 8;
    outz[(size_t)c * R + r0 + tx] = __float2bfloat16(tile[tx][ty + jj * 8]);
  }
}

// =====================================================================
// GEMM core v7 — m201-faithful 4-phase/K-tile schedule.
// 256(A rows,m) x 256(B rows,n) x BK=64, 512 thr = 8 waves (wm 0..1, wn 0..3),
// acc[8][4]. 2 x 64KB LDS dbuf, pieces laid out PHASE-CONTIGUOUS per buffer:
//   A(s,q) 8KB at s*16384+q*8192 (s = 32-k half, q = m-quadrant)
//   B(s)  16KB at 32768+s*16384 (staged as 2 x 8KB row-halves u)
// Row = 64B; swizzle slot = ks ^ ((row>>1)&3) (r5-verified 2-way/free),
// inverse applied on the global source column (rule #21).
// Per phase: stage 2 units of tile t+1 -> other buf (WAR-safe: freed at
// t-1's final barrier) | 4-8 ds_reads | barrier | lgkmcnt(0) |
// setprio(1) 16 MFMA setprio(0) | [W-vmcnt] | barrier.
// COUNTED END-OF-PHASE WAITS (the r5-r9 fix — issue->drain = 3-4 phases,
// above HBM latency at the fast fixed point):
//   W1 = vmcnt(4) end of ph2: drains tile t's P3,P4,P6 (issued t-1 ph3/ph4)
//   W2 = vmcnt(4) end of ph4: drains tile t+1's P1,P5a,P2,P5b (issued ph1/ph2)
// Tail: W1 -> vmcnt(0) at t=NT-1; W2 skipped. Never vmcnt(0) mid-loop.
// =====================================================================
__device__ __forceinline__ void gemm_core_v7(const char* __restrict__ Ag, const char* __restrict__ Bg,
                                             const int lda, const int ldb, const int NT,
                                             char* lds, f32x4 (&acc)[8][4])
{
  const int tid = threadIdx.x;
  const int l = tid & 63;
  const int w = tid >> 6;
  const int wm = w >> 2;                  // m-half 0..1
  const int wn = w & 3;                   // n-quarter 0..3
  const int lr = l & 15;
  const int ks = l >> 4;                  // 0..3 (16B k-slot)
  const int rswz = (ks ^ ((lr >> 1) & 3)) << 4;
  const int dst = tid * 16;

  // staging coords: thread -> piece-row pr = tid>>2, phys slot tid&3
  const size_t arow = (size_t)(((tid >> 8) & 1) * 128 + ((tid >> 2) & 63)); // wh*128 + rr  (pr = tid>>2, wh = pr>>6)
  const int csw = (((tid & 3) ^ ((tid >> 3) & 3)) << 4);   // inverse-swizzled src 16B col

  // A piece (s,q) of K-tile t_ -> buf + s*16384 + q*8192 (1 gl2lds/thread)
#define STG_A(t_, s_, q_, bufp) \
    GL2LDS(Ag + (arow + (q_) * 64) * (size_t)lda + (t_) * 128 + (s_) * 64 + csw, \
           (bufp) + (s_) * 16384 + (q_) * 8192 + dst)
  // B row-half u of k-half s of K-tile t_ -> buf + 32768 + s*16384 + u*8192
#define STG_B(t_, s_, u_, bufp) \
    GL2LDS(Bg + ((size_t)((u_) * 128) + (tid >> 2)) * (size_t)ldb + (t_) * 128 + (s_) * 64 + csw, \
           (bufp) + 32768 + (s_) * 16384 + (u_) * 8192 + dst)

  // ---- prologue: tile 0 -> buf0, queue order [P1,P5a | P2,P5b | P3,P6a | P4,P6b] ----
  STG_A(0, 0, 0, lds); STG_B(0, 0, 0, lds);
  STG_A(0, 0, 1, lds); STG_B(0, 0, 1, lds);
  STG_A(0, 1, 0, lds); STG_B(0, 1, 0, lds);
  STG_A(0, 1, 1, lds); STG_B(0, 1, 1, lds);
  asm volatile("s_waitcnt vmcnt(4)" ::: "memory");   // drain P1,P5a,P2,P5b of tile 0
  __builtin_amdgcn_s_barrier();

#pragma unroll 1
  for (int t = 0; t < NT; ++t) {
    char* cur = lds + ((t & 1) << 16);
    char* nb  = lds + (((t + 1) & 1) << 16);
    const bool pre = (t + 1 < NT);
    bf16x8 a[4], bv[4];

    // ================ phase 1: s=0, q=0 ================
    if (pre) { STG_A(t + 1, 0, 0, nb); STG_B(t + 1, 0, 0, nb); }
#pragma unroll
    for (int f = 0; f < 4; ++f)
      a[f] = *(const bf16x8*)(cur + wm * 4096 + f * 1024 + lr * 64 + rswz);
#pragma unroll
    for (int n = 0; n < 4; ++n)
      bv[n] = *(const bf16x8*)(cur + 32768 + wn * 4096 + n * 1024 + lr * 64 + rswz);
    __builtin_amdgcn_s_barrier();
    asm volatile("s_waitcnt lgkmcnt(0)" ::: "memory");
    __builtin_amdgcn_s_setprio(1);
#pragma unroll
    for (int f = 0; f < 4; ++f)
#pragma unroll
      for (int n = 0; n < 4; ++n)
        acc[f][n] = MFMA16(a[f], bv[n], acc[f][n]);
    __builtin_amdgcn_s_setprio(0);
    __builtin_amdgcn_s_barrier();

    // ================ phase 2: s=0, q=1 ================
    if (pre) { STG_A(t + 1, 0, 1, nb); STG_B(t + 1, 0, 1, nb); }
#pragma unroll
    for (int f = 0; f < 4; ++f)
      a[f] = *(const bf16x8*)(cur + 8192 + wm * 4096 + f * 1024 + lr * 64 + rswz);
    __builtin_amdgcn_s_barrier();
    asm volatile("s_waitcnt lgkmcnt(0)" ::: "memory");
    __builtin_amdgcn_s_setprio(1);
#pragma unroll
    for (int f = 0; f < 4; ++f)
#pragma unroll
      for (int n = 0; n < 4; ++n)
        acc[4 + f][n] = MFMA16(a[f], bv[n], acc[4 + f][n]);
    __builtin_amdgcn_s_setprio(0);
    // W1: drain tile t's P3,P4,P6 (issued 3-4 phases ago); keep t+1's ph1/ph2 in flight
    if (pre) asm volatile("s_waitcnt vmcnt(4)" ::: "memory");
    else     asm volatile("s_waitcnt vmcnt(0)" ::: "memory");
    __builtin_amdgcn_s_barrier();

    // ================ phase 3: s=1, q=0 ================
    if (pre) { STG_A(t + 1, 1, 0, nb); STG_B(t + 1, 1, 0, nb); }
#pragma unroll
    for (int f = 0; f < 4; ++f)
      a[f] = *(const bf16x8*)(cur + 16384 + wm * 4096 + f * 1024 + lr * 64 + rswz);
#pragma unroll
    for (int n = 0; n < 4; ++n)
      bv[n] = *(const bf16x8*)(cur + 32768 + 16384 + wn * 4096 + n * 1024 + lr * 64 + rswz);
    __builtin_amdgcn_s_barrier();
    asm volatile("s_waitcnt lgkmcnt(0)" ::: "memory");
    __builtin_amdgcn_s_setprio(1);
#pragma unroll
    for (int f = 0; f < 4; ++f)
#pragma unroll
      for (int n = 0; n < 4; ++n)
        acc[f][n] = MFMA16(a[f], bv[n], acc[f][n]);
    __builtin_amdgcn_s_setprio(0);
    __builtin_amdgcn_s_barrier();

    // ================ phase 4: s=1, q=1 ================
    if (pre) { STG_A(t + 1, 1, 1, nb); STG_B(t + 1, 1, 1, nb); }
#pragma unroll
    for (int f = 0; f < 4; ++f)
      a[f] = *(const bf16x8*)(cur + 24576 + wm * 4096 + f * 1024 + lr * 64 + rswz);
    __builtin_amdgcn_s_barrier();
    asm volatile("s_waitcnt lgkmcnt(0)" ::: "memory");
    __builtin_amdgcn_s_setprio(1);
#pragma unroll
    for (int f = 0; f < 4; ++f)
#pragma unroll
      for (int n = 0; n < 4; ++n)
        acc[4 + f][n] = MFMA16(a[f], bv[n], acc[4 + f][n]);
    __builtin_amdgcn_s_setprio(0);
    // W2: drain t+1's P1,P5a,P2,P5b (issued ph1/ph2); keep ph3/ph4 issues in flight
    if (pre) asm volatile("s_waitcnt vmcnt(4)" ::: "memory");
    __builtin_amdgcn_s_barrier();
  }
#undef STG_A
#undef STG_B
}

// ---------------- GEMM1: H[p][s][h] = gelu(x @ w1 + b1)  (A = weights) ----------------
__global__ __launch_bounds__(512, 2) void gemm1_kernel(
    const __hip_bfloat16* __restrict__ Xb, const __hip_bfloat16* __restrict__ W1T,
    const float* __restrict__ b1, __hip_bfloat16* __restrict__ Hbuf,
    const int* __restrict__ gidx, const int* __restrict__ psort)
{
  extern __shared__ char lds[];
  const int P = blockIdx.x;                 // 1024
  const int L = (P & 7) * 128 + (P >> 3);   // bijective XCD chunk remap
  const int p = psort[L >> 4];              // 16 tiles/pair, pair-clustered per XCD
  const int tl = L & 15;
  const int b = p >> 1;
  const int e = gidx[p];
  const int h0 = (tl >> 1) * 256;           // 8 h-tiles
  const int s0 = (tl & 1) * 256;            // 2 s-tiles
  const char* Ag = (const char*)(W1T + ((size_t)e * H_ + h0) * D_);
  const char* Bg = (const char*)(Xb + ((size_t)b * S_ + s0) * D_);
  f32x4 acc[8][4] = {};
  gemm_core_v7(Ag, Bg, D_ * 2, D_ * 2, D_ / 64, lds, acc);

  const int tid = threadIdx.x, l = tid & 63, w = tid >> 6;
  const int wm = w >> 2, wn = w & 3, lr = l & 15, q4 = ((l >> 4) & 3) << 2;
  const float* b1e = b1 + (size_t)e * H_ + h0;
  __hip_bfloat16* Hp = Hbuf + (size_t)p * S_ * H_ + h0;
#pragma unroll
  for (int m = 0; m < 8; ++m) {
    const int hl = wm * 128 + m * 16 + q4;          // feature offset (mult of 4)
    const float4 bias = *(const float4*)(b1e + hl);
#pragma unroll
    for (int n = 0; n < 4; ++n) {
      const int sl = s0 + wn * 64 + n * 16 + lr;    // s row
      ushort4 ov;
      ov.x = __builtin_bit_cast(unsigned short, __float2bfloat16(gelu_fast(acc[m][n][0] + bias.x)));
      ov.y = __builtin_bit_cast(unsigned short, __float2bfloat16(gelu_fast(acc[m][n][1] + bias.y)));
      ov.z = __builtin_bit_cast(unsigned short, __float2bfloat16(gelu_fast(acc[m][n][2] + bias.z)));
      ov.w = __builtin_bit_cast(unsigned short, __float2bfloat16(gelu_fast(acc[m][n][3] + bias.w)));
      *(ushort4*)(Hp + (size_t)sl * H_ + hl) = ov;
    }
  }
}

// ---------------- GEMM2: out[b][s][o] += gw * gelu(H @ w2 + b2)  (A = data) ----------------
// r7-verified epilogue: j along s, 16 lanes cover 16 consecutive o (WRITE 65 MB);
// 2 deterministic f32 atomic terms per output.
__global__ __launch_bounds__(512, 2) void gemm2_kernel(
    const __hip_bfloat16* __restrict__ Hbuf, const __hip_bfloat16* __restrict__ W2T,
    const float* __restrict__ b2, float* __restrict__ out,
    const int* __restrict__ gidx, const float* __restrict__ gwt,
    const int* __restrict__ psort)
{
  extern __shared__ char lds[];
  const int P = blockIdx.x;                 // 256 (1/CU)
  const int L = (P & 7) * 32 + (P >> 3);
  const int p = psort[L >> 2];              // 4 tiles/pair, expert-clustered per XCD
  const int tl = L & 3;
  const int b = p >> 1;
  const int e = gidx[p];
  const float gw = gwt[p];
  const int s0 = (tl >> 1) * 256;           // 2 s-tiles (m-axis)
  const int o0 = (tl & 1) * 256;            // 2 o-tiles (n-axis)
  const char* Ag = (const char*)(Hbuf + ((size_t)p * S_ + s0) * H_);
  const char* Bg = (const char*)(W2T + ((size_t)e * O_ + o0) * H_);
  f32x4 acc[8][4] = {};
  gemm_core_v7(Ag, Bg, H_ * 2, H_ * 2, H_ / 64, lds, acc);

  const int tid = threadIdx.x, l = tid & 63, w = tid >> 6;
  const int wm = w >> 2, wn = w & 3, lr = l & 15, q4 = ((l >> 4) & 3) << 2;
  const float* b2e = b2 + (size_t)e * O_ + o0;
#pragma unroll
  for (int m = 0; m < 8; ++m) {
    const int sl = s0 + wm * 128 + m * 16 + q4;     // s base for j=0..3
#pragma unroll
    for (int n = 0; n < 4; ++n) {
      const int ol = wn * 64 + n * 16 + lr;         // o (16 consecutive per lane group)
      const float bias = b2e[ol];
      float* dstp = out + ((size_t)b * S_ + sl) * O_ + o0 + ol;
#pragma unroll
      for (int j = 0; j < 4; ++j)
        atomicAdd(dstp + (size_t)j * O_, gelu_fast(acc[m][n][j] + bias) * gw);
    }
  }
}

// ---------------- sentinel (ws too small signal) ----------------
__global__ void sentinel_kernel(float* out, int n) {
  int i = blockIdx.x * blockDim.x + threadIdx.x;
  for (; i < n; i += gridDim.x * blockDim.x) out[i] = 1.0e6f;
}

extern "C" void kernel_launch(void* const* d_in, const int* in_sizes, int n_in,
                              void* d_out, int out_size, void* d_ws, size_t ws_size,
                              hipStream_t stream)
{
  const float* x      = (const float*)d_in[0];
  const float* attn_w = (const float*)d_in[1];
  // d_in[2] = attn_b: scalar, softmax-invariant -> unused
  const float* gate_w = (const float*)d_in[3];
  const float* gate_b = (const float*)d_in[4];
  const float* w1     = (const float*)d_in[5];
  const float* b1     = (const float*)d_in[6];
  const float* w2     = (const float*)d_in[7];
  const float* b2     = (const float*)d_in[8];
  float* out = (float*)d_out;

  char* ws = (char*)d_ws;
  const size_t OFF_GIDX = 0;     // 256 B
  const size_t OFF_GWT  = 256;   // 256 B
  const size_t OFF_PSRT = 512;   // 256 B
  const size_t OFF_X    = 1024;
  const size_t SZ_X     = (size_t)B_ * S_ * D_ * 2;   // 16 MB
  const size_t OFF_W1T  = OFF_X + SZ_X;
  const size_t SZ_W1T   = (size_t)E_ * H_ * D_ * 2;   // 16 MB
  const size_t OFF_W2T  = OFF_W1T + SZ_W1T;
  const size_t SZ_W2T   = (size_t)E_ * O_ * H_ * 2;   // 16 MB
  const size_t OFF_H    = OFF_W2T + SZ_W2T;
  const size_t PAIR_H   = (size_t)S_ * H_ * 2;        // 2 MB per pair

  if (OFF_H + 64 * PAIR_H > ws_size) {
    hipLaunchKernelGGL(sentinel_kernel, dim3(256), dim3(256), 0, stream, out, out_size);
    return;
  }

  int*   gidx  = (int*)(ws + OFF_GIDX);
  float* gwt   = (float*)(ws + OFF_GWT);
  int*   psort = (int*)(ws + OFF_PSRT);
  __hip_bfloat16* xb   = (__hip_bfloat16*)(ws + OFF_X);
  __hip_bfloat16* w1T  = (__hip_bfloat16*)(ws + OFF_W1T);
  __hip_bfloat16* w2T  = (__hip_bfloat16*)(ws + OFF_W2T);
  __hip_bfloat16* Hbuf = (__hip_bfloat16*)(ws + OFF_H);
  // pool-chain scratch overlaid on Hbuf region (consumed before gemm1 writes it)
  float* scores = (float*)(ws + OFF_H);            // 64 KB
  float* aw     = (float*)(ws + OFF_H + 65536);    // 64 KB
  float* pooled = (float*)(ws + OFF_H + 131072);   // 64 KB

  // 128 KiB dynamic LDS opt-in
  (void)hipFuncSetAttribute((const void*)gemm1_kernel, hipFuncAttributeMaxDynamicSharedMemorySize, 131072);
  (void)hipFuncSetAttribute((const void*)gemm2_kernel, hipFuncAttributeMaxDynamicSharedMemorySize, 131072);

  hipLaunchKernelGGL(cast_score_kernel, dim3(B_ * S_ / 8), dim3(256), 0, stream,
                     x, attn_w, (ushort*)xb, scores);
  hipLaunchKernelGGL(softmax_aw_kernel, dim3(B_), dim3(512), 0, stream, scores, aw);
  hipLaunchKernelGGL(pool_kernel, dim3(4, B_), dim3(512), 0, stream, x, aw, pooled);
  hipLaunchKernelGGL(gate_psort_kernel, dim3(1), dim3(256), 0, stream,
                     pooled, gate_w, gate_b, gidx, gwt, psort);
  hipLaunchKernelGGL(transpose_cast_kernel, dim3(H_ / 32, D_ / 32, E_), dim3(32, 8), 0, stream,
                     w1, w1T, D_, H_);
  hipLaunchKernelGGL(transpose_cast_kernel, dim3(O_ / 32, H_ / 32, E_), dim3(32, 8), 0, stream,
                     w2, w2T, H_, O_);
  hipMemsetAsync(d_out, 0, (size_t)out_size * sizeof(float), stream);

  hipLaunchKernelGGL(gemm1_kernel, dim3(1024), dim3(512), 131072, stream,
                     xb, w1T, b1, Hbuf, gidx, psort);
  hipLaunchKernelGGL(gemm2_kernel, dim3(256), dim3(512), 131072, stream,
                     Hbuf, w2T, b2, out, gidx, gwt, psort);
}